// Round 3
// baseline (704.310 us; speedup 1.0000x reference)
//
#include <hip/hip_runtime.h>
#include <hip/hip_cooperative_groups.h>

namespace cg = cooperative_groups;

#define NROWS 800000
#define SEGROWS 100000
#define NBLK 256
#define RPB 3125          // rows/block in phase A; 32 blocks per segment (segment-aligned)
#define NTILES 3125       // phase D: 800000 / 256 exactly
#define PART_BASE 8192
#define PART_STRIDE 4160
// ws float layout:
//   [0..4096)     M2            (phase B)
//   [4096..4608)  segment sums  (phase B)
//   [4608..5120)  tb fp32       (phase C)
//   [5120..7168)  wpb bf16 64x64 row-major [c][k] (phase C)
//   [8192.. )     per-block partials, stride 4160 (4096 M2 + 64 segsum)

typedef __attribute__((ext_vector_type(8))) short bf16x8;
typedef __attribute__((ext_vector_type(4))) float f32x4;
typedef __attribute__((ext_vector_type(4))) short short4v;

__device__ inline unsigned short f2bf(float f) { // RNE fp32 -> bf16
    unsigned u = __builtin_bit_cast(unsigned, f);
    return (unsigned short)((u + 0x7FFFu + ((u >> 16) & 1u)) >> 16);
}

__global__ __launch_bounds__(256, 2)
void kfused(const float* __restrict__ x, const int* __restrict__ o,
            const float* __restrict__ w2, const float* __restrict__ b2,
            const float* __restrict__ w1, const float* __restrict__ b1,
            const float* __restrict__ gamma, const float* __restrict__ beta,
            float* __restrict__ out, float* __restrict__ ws)
{
    __shared__ __align__(16) float smem[5120]; // 20 KB, reused across phases
    cg::grid_group grid = cg::this_grid();
    const int t = threadIdx.x, b = blockIdx.x;
    const int w = t >> 6, lane = t & 63;
    const int c4 = t & 15, g = t >> 4;
    const int cl = lane & 15, qd = lane >> 4;

    float* m2   = ws;
    float* ssum = ws + 4096;
    float* tb   = ws + 4608;
    unsigned short* wpb = (unsigned short*)(ws + 5120);
    float* part = ws + PART_BASE;

    // ================= Phase A: per-block X^T X + segment sums =================
    {
        short* xt = (short*)smem;                // xt[col][row], stride 136 shorts
        const float4* X4 = (const float4*)x;
        size_t r0 = (size_t)b * RPB;

        f32x4 acc[4][4];
#pragma unroll
        for (int p = 0; p < 4; ++p)
#pragma unroll
            for (int q = 0; q < 4; ++q) acc[p][q] = (f32x4){0.f, 0.f, 0.f, 0.f};
        float s0 = 0, s1 = 0, s2 = 0, s3 = 0;

        for (int tile = 0; tile < RPB; tile += 128) {
            int nr = min(128, RPB - tile);       // 128 (24x) then 53
            __syncthreads();                     // previous tile's frag reads done
#pragma unroll
            for (int h = 0; h < 2; ++h) {        // 4 rows x 4 cols per piece, transposed
                int rg = 8 * g + 4 * h;
                float4 v[4];
#pragma unroll
                for (int i = 0; i < 4; ++i) {
                    int r = rg + i;
                    if (r < nr) {
                        v[i] = X4[(r0 + tile + r) * 16 + c4];
                        s0 += v[i].x; s1 += v[i].y; s2 += v[i].z; s3 += v[i].w;
                    } else v[i] = make_float4(0.f, 0.f, 0.f, 0.f);
                }
#pragma unroll
                for (int j = 0; j < 4; ++j) {
                    short4v pk;
                    pk[0] = (short)f2bf(((const float*)&v[0])[j]);
                    pk[1] = (short)f2bf(((const float*)&v[1])[j]);
                    pk[2] = (short)f2bf(((const float*)&v[2])[j]);
                    pk[3] = (short)f2bf(((const float*)&v[3])[j]);
                    *(short4v*)&xt[(4 * c4 + j) * 136 + rg] = pk;
                }
            }
            __syncthreads();
            bf16x8 f[4];                          // wave w: k-chunk rows 32w..32w+31
#pragma unroll
            for (int c0 = 0; c0 < 4; ++c0)
                f[c0] = *(const bf16x8*)&xt[(16 * c0 + cl) * 136 + 32 * w + 8 * qd];
#pragma unroll
            for (int p = 0; p < 4; ++p)
#pragma unroll
                for (int q = 0; q < 4; ++q)
                    acc[p][q] = __builtin_amdgcn_mfma_f32_16x16x32_bf16(f[p], f[q], acc[p][q], 0, 0, 0);
        }

        __syncthreads();                          // xt dead; reuse smem
        ((float4*)(smem + 4096))[t] = make_float4(s0, s1, s2, s3);
        if (w == 0) {
#pragma unroll
            for (int p = 0; p < 4; ++p)
#pragma unroll
                for (int q = 0; q < 4; ++q)
#pragma unroll
                    for (int i = 0; i < 4; ++i)
                        smem[(16 * p + 4 * qd + i) * 64 + 16 * q + cl] = acc[p][q][i];
        }
        __syncthreads();
        for (int ww = 1; ww < 4; ++ww) {
            if (w == ww) {
#pragma unroll
                for (int p = 0; p < 4; ++p)
#pragma unroll
                    for (int q = 0; q < 4; ++q)
#pragma unroll
                        for (int i = 0; i < 4; ++i)
                            smem[(16 * p + 4 * qd + i) * 64 + 16 * q + cl] += acc[p][q][i];
            }
            __syncthreads();
        }
        if (t < 64) {                             // segment-sum cross-lane reduce
            float s = 0;
#pragma unroll
            for (int u = 0; u < 16; ++u) s += smem[4096 + 4 * ((t >> 2) + 16 * u) + (t & 3)];
            part[(size_t)b * PART_STRIDE + 4096 + t] = s;
        }
        for (int f2 = t; f2 < 4096; f2 += 256)
            part[(size_t)b * PART_STRIDE + f2] = smem[f2];
    }
    __threadfence();
    grid.sync();

    // ================= Phase B: reduce partials =================
    if (b < 16) {
        int e = b * 256 + t;
        float s = 0;
#pragma unroll 4
        for (int i = 0; i < NBLK; ++i) s += part[(size_t)i * PART_STRIDE + e];
        m2[e] = s;
    } else if (b < 18) {
        int idx = (b - 16) * 256 + t;             // (seg, channel)
        int sg = idx >> 6, c = idx & 63;
        float s = 0;
#pragma unroll 4
        for (int i = 0; i < 32; ++i) s += part[(size_t)(sg * 32 + i) * PART_STRIDE + 4096 + c];
        ssum[idx] = s;
    }
    __threadfence();
    grid.sync();

    // ================= Phase C: solve (block 0 only) =================
    if (b == 0) {
        float* means = smem;         // 512
        float* hb    = smem + 512;   // 512
        float* cv    = smem + 1024;  // 512
        float* Sx    = smem + 1536;  // 64
        float* cnts  = smem + 1600;  // 8
        float* muS   = smem + 1608;  // 64
        float* sS    = smem + 1672;  // 64
        float* q1p   = smem + 1736;  // 256
        if (t < 8) cnts[t] = (float)(o[t] - (t ? o[t - 1] : 0));
        __syncthreads();
        for (int i = t; i < 512; i += 256) means[i] = ssum[i] / cnts[i >> 6];
        __syncthreads();
        int c = t & 63, gq = t >> 6;
        for (int bb = gq; bb < 8; bb += 4) {      // h = relu(means @ w2.T + b2)
            float a = b2[c];
            for (int k = 0; k < 64; ++k) a = fmaf(means[bb * 64 + k], w2[c * 64 + k], a);
            hb[bb * 64 + c] = fmaxf(a, 0.f);
        }
        __syncthreads();
        for (int bb = gq; bb < 8; bb += 4) {      // cvec = W1b @ h + b1
            float a = b1[c];
            for (int k = 0; k < 64; ++k) a = fmaf(hb[bb * 64 + k], w1[c * 128 + 64 + k], a);
            cv[bb * 64 + c] = a;
        }
        __syncthreads();
        if (t < 64) {
            float s = 0;
            for (int bb = 0; bb < 8; ++bb) s += ssum[bb * 64 + t];
            Sx[t] = s;
        }
        __syncthreads();
        {                                          // q1 = w_c^T M2 w_c, split over j
            float p = 0;
            for (int j = gq * 16; j < gq * 16 + 16; ++j) {
                float vj = 0;
                for (int k = 0; k < 64; ++k) vj = fmaf(w1[c * 128 + k], m2[j * 64 + k], vj);
                p = fmaf(w1[c * 128 + j], vj, p);
            }
            q1p[gq * 64 + c] = p;
        }
        __syncthreads();
        if (t < 64) {
            const float Nf = (float)NROWS;
            float mu = 0;
            for (int k = 0; k < 64; ++k) mu = fmaf(w1[t * 128 + k], Sx[k], mu);
            float q2 = 0, q3 = 0, msum = 0;
            for (int bb = 0; bb < 8; ++bb) {
                float gv = cv[bb * 64 + t];
                msum += cnts[bb] * gv;
                q3 = fmaf(cnts[bb] * gv, gv, q3);
                float dot = 0;
                for (int k = 0; k < 64; ++k) dot = fmaf(w1[t * 128 + k], ssum[bb * 64 + k], dot);
                q2 = fmaf(2.f * gv, dot, q2);
            }
            mu = (mu + msum) / Nf;
            float q1 = q1p[t] + q1p[64 + t] + q1p[128 + t] + q1p[192 + t];
            float var = (q1 + q2 + q3) / Nf - mu * mu;
            float s = gamma[t] * rsqrtf(var + 1e-5f);
            muS[t] = mu; sS[t] = s;
        }
        __syncthreads();
        for (int f = t; f < 4096; f += 256)        // W' bf16, row-major [c][k]
            wpb[f] = f2bf(w1[(f >> 6) * 128 + (f & 63)] * sS[f >> 6]);
        for (int f = t; f < 512; f += 256)
            tb[f] = (cv[f] - muS[f & 63]) * sS[f & 63] + beta[f & 63];
    }
    __threadfence();
    grid.sync();

    // ================= Phase D: out = relu(x @ W'^T + tb[seg]) =================
    {
        short* bt  = (short*)smem;                 // 64x72 shorts = 9216 B
        float* tbs = smem + 2304;                  // 512 floats
        for (int f = t; f < 512; f += 256) {
            uint4 vv = ((const uint4*)wpb)[f];
            *(uint4*)&bt[(f >> 3) * 72 + (f & 7) * 8] = vv;
        }
        for (int f = t; f < 512; f += 256) tbs[f] = tb[f];
        __syncthreads();

        bf16x8 B[4][2];
#pragma unroll
        for (int n = 0; n < 4; ++n)
#pragma unroll
            for (int k0 = 0; k0 < 2; ++k0)
                B[n][k0] = *(const bf16x8*)&bt[(16 * n + cl) * 72 + 32 * k0 + 8 * qd];

        for (int tt = b; tt < NTILES; tt += NBLK) {
            int rbase = tt * 256 + 64 * w;
            f32x4 acc[4][4];
#pragma unroll
            for (int m = 0; m < 4; ++m)
#pragma unroll
                for (int n = 0; n < 4; ++n) acc[m][n] = (f32x4){0.f, 0.f, 0.f, 0.f};

#pragma unroll
            for (int m = 0; m < 4; ++m) {
                const float* rp = x + (size_t)(rbase + 16 * m + cl) * 64 + 8 * qd;
                float4 u0 = *(const float4*)(rp);
                float4 u1 = *(const float4*)(rp + 4);
                float4 u2 = *(const float4*)(rp + 32);
                float4 u3 = *(const float4*)(rp + 36);
                bf16x8 A0, A1;
                A0[0] = (short)f2bf(u0.x); A0[1] = (short)f2bf(u0.y);
                A0[2] = (short)f2bf(u0.z); A0[3] = (short)f2bf(u0.w);
                A0[4] = (short)f2bf(u1.x); A0[5] = (short)f2bf(u1.y);
                A0[6] = (short)f2bf(u1.z); A0[7] = (short)f2bf(u1.w);
                A1[0] = (short)f2bf(u2.x); A1[1] = (short)f2bf(u2.y);
                A1[2] = (short)f2bf(u2.z); A1[3] = (short)f2bf(u2.w);
                A1[4] = (short)f2bf(u3.x); A1[5] = (short)f2bf(u3.y);
                A1[6] = (short)f2bf(u3.z); A1[7] = (short)f2bf(u3.w);
#pragma unroll
                for (int n = 0; n < 4; ++n) {
                    acc[m][n] = __builtin_amdgcn_mfma_f32_16x16x32_bf16(A0, B[n][0], acc[m][n], 0, 0, 0);
                    acc[m][n] = __builtin_amdgcn_mfma_f32_16x16x32_bf16(A1, B[n][1], acc[m][n], 0, 0, 0);
                }
            }

            int seg0 = rbase / SEGROWS;
            int bnd = (seg0 + 1) * SEGROWS;
            int seg1 = min(seg0 + 1, 7);
            float tA[4], tB[4];
#pragma unroll
            for (int n = 0; n < 4; ++n) {
                tA[n] = tbs[seg0 * 64 + 16 * n + cl];
                tB[n] = tbs[seg1 * 64 + 16 * n + cl];
            }
#pragma unroll
            for (int m = 0; m < 4; ++m)
#pragma unroll
                for (int i = 0; i < 4; ++i) {
                    int grow = rbase + 16 * m + 4 * qd + i;
                    bool hi = grow >= bnd;
#pragma unroll
                    for (int n = 0; n < 4; ++n) {
                        float tv = hi ? tB[n] : tA[n];
                        float vv = fmaxf(acc[m][n][i] + tv, 0.f);
                        out[(size_t)grow * 64 + 16 * n + cl] = vv;
                    }
                }
        }
    }
}

extern "C" void kernel_launch(void* const* d_in, const int* in_sizes, int n_in,
                              void* d_out, int out_size, void* d_ws, size_t ws_size,
                              hipStream_t stream)
{
    const float* x  = (const float*)d_in[0];
    const int*   o  = (const int*)d_in[1];
    const float* w2 = (const float*)d_in[2];
    const float* b2 = (const float*)d_in[3];
    const float* w1 = (const float*)d_in[4];
    const float* b1 = (const float*)d_in[5];
    const float* gm = (const float*)d_in[6];
    const float* bt = (const float*)d_in[7];
    float* out = (float*)d_out;
    float* ws  = (float*)d_ws;

    void* args[] = {(void*)&x, (void*)&o, (void*)&w2, (void*)&b2, (void*)&w1,
                    (void*)&b1, (void*)&gm, (void*)&bt, (void*)&out, (void*)&ws};
    hipLaunchCooperativeKernel((void*)kfused, dim3(NBLK), dim3(256), args, 0, stream);
}

// Round 4
// 513.571 us; speedup vs baseline: 1.3714x; 1.3714x over previous
//
#include <hip/hip_runtime.h>

#define NROWS 800000
#define SEGROWS 100000
#define K1_BLOCKS 800
#define K1_ROWS 1000      // 100 blocks per segment (segment-aligned)
#define NTILES 3125       // k3: 800000 / 256
#define PART_BASE 8192
#define PART_STRIDE 4160
#define XB_BASE (PART_BASE + K1_BLOCKS * PART_STRIDE)   // floats; xb = ushort[NROWS*64]
// ws float layout:
//   [0..4096)     M2                (k2a)
//   [4096..4608)  segment sums      (k2a)
//   [4608..5120)  tb fp32           (k2b)
//   [5120..7168)  wpb bf16 64x64 row-major [c][k] (k2b)
//   [8192..8192+800*4160)  per-block partials (k1)
//   [XB_BASE..)   xb: bf16 copy of x, row-major (k1)

typedef __attribute__((ext_vector_type(8))) short bf16x8;
typedef __attribute__((ext_vector_type(4))) float f32x4;
typedef __attribute__((ext_vector_type(4))) short short4v;

__device__ inline unsigned short f2bf(float f) { // RNE fp32 -> bf16
    unsigned u = __builtin_bit_cast(unsigned, f);
    return (unsigned short)((u + 0x7FFFu + ((u >> 16) & 1u)) >> 16);
}

// ---------------- K1: X^T X partials + segment sums + bf16 x copy ----------------
__global__ __launch_bounds__(256, 3)
void k1_stats(const float* __restrict__ x, float* __restrict__ part,
              unsigned short* __restrict__ xb)
{
    __shared__ __align__(16) float smem[5120];   // 20 KB
    short* xt = (short*)smem;                    // xt[col][row], stride 136 shorts
    const float4* X4 = (const float4*)x;
    int t = threadIdx.x, w = t >> 6, lane = t & 63;
    int c4 = t & 15, g = t >> 4;
    int cl = lane & 15, qd = lane >> 4;
    size_t r0 = (size_t)blockIdx.x * K1_ROWS;

    f32x4 acc[4][4];
#pragma unroll
    for (int p = 0; p < 4; ++p)
#pragma unroll
        for (int q = 0; q < 4; ++q) acc[p][q] = (f32x4){0.f, 0.f, 0.f, 0.f};
    float s0 = 0, s1 = 0, s2 = 0, s3 = 0;

    for (int tile = 0; tile < K1_ROWS; tile += 128) {
        int nr = min(128, K1_ROWS - tile);       // 128 (x7) then 104
        __syncthreads();
#pragma unroll
        for (int h = 0; h < 2; ++h) {            // 4 rows x 4 cols per piece
            int rg = 8 * g + 4 * h;
            float4 v[4];
#pragma unroll
            for (int i = 0; i < 4; ++i) {
                int r = rg + i;
                if (r < nr) {
                    v[i] = X4[(r0 + tile + r) * 16 + c4];
                    s0 += v[i].x; s1 += v[i].y; s2 += v[i].z; s3 += v[i].w;
                } else v[i] = make_float4(0.f, 0.f, 0.f, 0.f);
            }
            unsigned short bf[4][4];
#pragma unroll
            for (int i = 0; i < 4; ++i) {
                bf[i][0] = f2bf(v[i].x); bf[i][1] = f2bf(v[i].y);
                bf[i][2] = f2bf(v[i].z); bf[i][3] = f2bf(v[i].w);
            }
#pragma unroll
            for (int j = 0; j < 4; ++j) {        // transposed -> LDS (MFMA frags)
                short4v pk;
                pk[0] = (short)bf[0][j]; pk[1] = (short)bf[1][j];
                pk[2] = (short)bf[2][j]; pk[3] = (short)bf[3][j];
                *(short4v*)&xt[(4 * c4 + j) * 136 + rg] = pk;
            }
#pragma unroll
            for (int i = 0; i < 4; ++i) {        // row-major bf16 -> global xb
                int r = rg + i;
                if (r < nr) {
                    unsigned short u4[4] = {bf[i][0], bf[i][1], bf[i][2], bf[i][3]};
                    *(uint2*)&xb[(r0 + tile + r) * 64 + 4 * c4] = *(const uint2*)u4;
                }
            }
        }
        __syncthreads();
        bf16x8 f[4];                              // wave w: k-rows 32w..32w+31
#pragma unroll
        for (int c0 = 0; c0 < 4; ++c0)
            f[c0] = *(const bf16x8*)&xt[(16 * c0 + cl) * 136 + 32 * w + 8 * qd];
#pragma unroll
        for (int p = 0; p < 4; ++p)
#pragma unroll
            for (int q = 0; q < 4; ++q)
                acc[p][q] = __builtin_amdgcn_mfma_f32_16x16x32_bf16(f[p], f[q], acc[p][q], 0, 0, 0);
    }

    __syncthreads();                              // xt dead; reuse smem
    ((float4*)(smem + 4096))[t] = make_float4(s0, s1, s2, s3);
    if (w == 0) {
#pragma unroll
        for (int p = 0; p < 4; ++p)
#pragma unroll
            for (int q = 0; q < 4; ++q)
#pragma unroll
                for (int i = 0; i < 4; ++i)
                    smem[(16 * p + 4 * qd + i) * 64 + 16 * q + cl] = acc[p][q][i];
    }
    __syncthreads();
    for (int ww = 1; ww < 4; ++ww) {
        if (w == ww) {
#pragma unroll
            for (int p = 0; p < 4; ++p)
#pragma unroll
                for (int q = 0; q < 4; ++q)
#pragma unroll
                    for (int i = 0; i < 4; ++i)
                        smem[(16 * p + 4 * qd + i) * 64 + 16 * q + cl] += acc[p][q][i];
        }
        __syncthreads();
    }
    if (t < 64) {                                 // segment-sum cross-lane reduce
        float s = 0;
#pragma unroll
        for (int u = 0; u < 16; ++u) s += smem[4096 + 4 * ((t >> 2) + 16 * u) + (t & 3)];
        part[(size_t)blockIdx.x * PART_STRIDE + 4096 + t] = s;
    }
    for (int f2 = t; f2 < 4096; f2 += 256)
        part[(size_t)blockIdx.x * PART_STRIDE + f2] = smem[f2];
}

// ---------------- K2a: reduce partials -> M2, segment sums ----------------
__global__ __launch_bounds__(256)
void k2a_reduce(const float* __restrict__ part, float* __restrict__ m2,
                float* __restrict__ ssum)
{
    int t = threadIdx.x, b = blockIdx.x;
    if (b < 16) {
        int e = b * 256 + t;
        float s = 0;
#pragma unroll 8
        for (int i = 0; i < K1_BLOCKS; ++i) s += part[(size_t)i * PART_STRIDE + e];
        m2[e] = s;
    } else {
        int idx = (b - 16) * 256 + t;             // (seg, channel)
        int sg = idx >> 6, c = idx & 63;
        float s = 0;
#pragma unroll 8
        for (int i = 0; i < 100; ++i) s += part[(size_t)(sg * 100 + i) * PART_STRIDE + 4096 + c];
        ssum[idx] = s;
    }
}

// ---------------- K2b: tiny algebra -> wpb (bf16), tb ----------------
__global__ __launch_bounds__(256)
void k2b_solve(const int* __restrict__ o,
               const float* __restrict__ w2, const float* __restrict__ b2,
               const float* __restrict__ w1, const float* __restrict__ b1,
               const float* __restrict__ gamma, const float* __restrict__ beta,
               const float* __restrict__ m2, const float* __restrict__ ssum,
               unsigned short* __restrict__ wpb, float* __restrict__ tbout)
{
    __shared__ float means[512], hb[512], cv[512], Sx[64], cnts[8], muS[64], sS[64], q1p[256];
    int t = threadIdx.x;
    if (t < 8) cnts[t] = (float)(o[t] - (t ? o[t - 1] : 0));
    __syncthreads();
    for (int i = t; i < 512; i += 256) means[i] = ssum[i] / cnts[i >> 6];
    __syncthreads();
    int c = t & 63, g = t >> 6;
    for (int b = g; b < 8; b += 4) {
        float a = b2[c];
        for (int k = 0; k < 64; ++k) a = fmaf(means[b * 64 + k], w2[c * 64 + k], a);
        hb[b * 64 + c] = fmaxf(a, 0.f);
    }
    __syncthreads();
    for (int b = g; b < 8; b += 4) {
        float a = b1[c];
        for (int k = 0; k < 64; ++k) a = fmaf(hb[b * 64 + k], w1[c * 128 + 64 + k], a);
        cv[b * 64 + c] = a;
    }
    __syncthreads();
    if (t < 64) {
        float s = 0;
        for (int b = 0; b < 8; ++b) s += ssum[b * 64 + t];
        Sx[t] = s;
    }
    __syncthreads();
    {
        float p = 0;
        for (int j = g * 16; j < g * 16 + 16; ++j) {
            float vj = 0;
            for (int k = 0; k < 64; ++k) vj = fmaf(w1[c * 128 + k], m2[j * 64 + k], vj);
            p = fmaf(w1[c * 128 + j], vj, p);
        }
        q1p[g * 64 + c] = p;
    }
    __syncthreads();
    if (t < 64) {
        const float Nf = (float)NROWS;
        float mu = 0;
        for (int k = 0; k < 64; ++k) mu = fmaf(w1[t * 128 + k], Sx[k], mu);
        float q2 = 0, q3 = 0, msum = 0;
        for (int b = 0; b < 8; ++b) {
            float gv = cv[b * 64 + t];
            msum += cnts[b] * gv;
            q3 = fmaf(cnts[b] * gv, gv, q3);
            float dot = 0;
            for (int k = 0; k < 64; ++k) dot = fmaf(w1[t * 128 + k], ssum[b * 64 + k], dot);
            q2 = fmaf(2.f * gv, dot, q2);
        }
        mu = (mu + msum) / Nf;
        float q1 = q1p[t] + q1p[64 + t] + q1p[128 + t] + q1p[192 + t];
        float var = (q1 + q2 + q3) / Nf - mu * mu;
        float s = gamma[t] * rsqrtf(var + 1e-5f);
        muS[t] = mu; sS[t] = s;
    }
    __syncthreads();
    for (int f = t; f < 4096; f += 256)
        wpb[f] = f2bf(w1[(f >> 6) * 128 + (f & 63)] * sS[f >> 6]);
    for (int f = t; f < 512; f += 256)
        tbout[f] = (cv[f] - muS[f & 63]) * sS[f & 63] + beta[f & 63];
}

// ---------------- K3: out = relu(xb @ W'^T + tb[seg]), A=W' B=x ----------------
// C layout: channel = 16p + 4*qd + i (4 consecutive per lane -> float4 stores),
//           x-row   = rowbase + cl.
__global__ __launch_bounds__(256, 4)
void k3_gemm(const unsigned short* __restrict__ xb, const unsigned short* __restrict__ wpb,
             const float* __restrict__ tb, float* __restrict__ out)
{
    __shared__ __align__(16) short bt[64 * 72];  // W' frags, stride 72 shorts
    __shared__ __align__(16) float tbs[512];
    int t = threadIdx.x, lane = t & 63, w = t >> 6;
    int cl = lane & 15, qd = lane >> 4;
    size_t r0 = (size_t)blockIdx.x * 256;

    for (int f = t; f < 512; f += 256) {         // stage W' (8 KB)
        uint4 vv = ((const uint4*)wpb)[f];
        *(uint4*)&bt[(f >> 3) * 72 + (f & 7) * 8] = vv;
    }
    for (int f = t; f < 512; f += 256) tbs[f] = tb[f];
    __syncthreads();

    bf16x8 Wf[4][2];                              // A-frags: W'[16p+cl][8qd+j+32kh]
#pragma unroll
    for (int p = 0; p < 4; ++p)
#pragma unroll
        for (int kh = 0; kh < 2; ++kh)
            Wf[p][kh] = *(const bf16x8*)&bt[(16 * p + cl) * 72 + 32 * kh + 8 * qd];

    int rbase = (int)r0 + 64 * w;
#pragma unroll
    for (int rt = 0; rt < 4; ++rt) {
        int row16 = rbase + 16 * rt;
        int r = row16 + cl;                       // this lane's x-row
        // B-frags: x[r][8qd+j+32kh], 16 B contiguous bf16
        const bf16x8 B0 = *(const bf16x8*)&xb[(size_t)r * 64 + 8 * qd];
        const bf16x8 B1 = *(const bf16x8*)&xb[(size_t)r * 64 + 32 + 8 * qd];
        int sg = r / SEGROWS;                     // per-lane; boundary-safe by construction
        f32x4 acc[4];
#pragma unroll
        for (int p = 0; p < 4; ++p) acc[p] = (f32x4){0.f, 0.f, 0.f, 0.f};
#pragma unroll
        for (int p = 0; p < 4; ++p) {
            acc[p] = __builtin_amdgcn_mfma_f32_16x16x32_bf16(Wf[p][0], B0, acc[p], 0, 0, 0);
            acc[p] = __builtin_amdgcn_mfma_f32_16x16x32_bf16(Wf[p][1], B1, acc[p], 0, 0, 0);
        }
#pragma unroll
        for (int p = 0; p < 4; ++p) {
            f32x4 tv = *(const f32x4*)&tbs[sg * 64 + 16 * p + 4 * qd];
            float4 res;
            res.x = fmaxf(acc[p][0] + tv[0], 0.f);
            res.y = fmaxf(acc[p][1] + tv[1], 0.f);
            res.z = fmaxf(acc[p][2] + tv[2], 0.f);
            res.w = fmaxf(acc[p][3] + tv[3], 0.f);
            *(float4*)&out[(size_t)r * 64 + 16 * p + 4 * qd] = res;
        }
    }
}

extern "C" void kernel_launch(void* const* d_in, const int* in_sizes, int n_in,
                              void* d_out, int out_size, void* d_ws, size_t ws_size,
                              hipStream_t stream)
{
    const float* x  = (const float*)d_in[0];
    const int*   o  = (const int*)d_in[1];
    const float* w2 = (const float*)d_in[2];
    const float* b2 = (const float*)d_in[3];
    const float* w1 = (const float*)d_in[4];
    const float* b1 = (const float*)d_in[5];
    const float* gm = (const float*)d_in[6];
    const float* bt = (const float*)d_in[7];
    float* out = (float*)d_out;
    float* ws  = (float*)d_ws;

    float*          m2g  = ws;
    float*          ssum = ws + 4096;
    float*          tbv  = ws + 4608;
    unsigned short* wpb  = (unsigned short*)(ws + 5120);
    float*          part = ws + PART_BASE;
    unsigned short* xb   = (unsigned short*)(ws + XB_BASE);

    k1_stats<<<K1_BLOCKS, 256, 0, stream>>>(x, part, xb);
    k2a_reduce<<<18, 256, 0, stream>>>(part, m2g, ssum);
    k2b_solve<<<1, 256, 0, stream>>>(o, w2, b2, w1, b1, gm, bt, m2g, ssum, wpb, tbv);
    k3_gemm<<<NTILES, 256, 0, stream>>>(xb, wpb, tbv, out);
}